// Round 7
// baseline (461.638 us; speedup 1.0000x reference)
//
#include <hip/hip_runtime.h>
#include <cstdint>

// MoE: B=16384 rows, D=2048 feat, E=16 experts, C=64 classes/expert.
// All math fp32 (argmax outputs can't tolerate bf16 error vs np reference).
// R7: kill spills by keeping NO prefetch registers live across barriers
// (R6: coarse pw[4] live across 2 barriers -> acc spilled -> 85MB scratch
// writes, 177us; expert pf[8]+acc64 ditto). Staging loads are transient
// (load -> LDS -> die); TLP hides the latency. Expert keeps the 8-wide row
// tile (LDS-pipe-bound: 4x4=2B/FMA=81us floor vs 8x8=1B/FMA=41us floor;
// DS pipe is per-CU, VALU per-SIMD -> 3:1 at 4x4, model matches R3/R5).
static constexpr int B_ = 16384;
static constexpr int D_ = 2048;
static constexpr int E_ = 16;
static constexpr int C_ = 64;

// ---------------- fused coarse router ----------------
// Block = 8 rows (4 waves x 2 rows), 2048 blocks. Lanes span K (float4
// coalesced). Weight K-chunk (16x256) staged in LDS via transient regs
// between the two barriers. Epilogue: split-halves shuffle reduction (lane
// owns expert bitrev4(lane&15)), argmax, compaction, last block builds the
// expert-GEMM schedule. Epilogue logic verified in R4/R6.
__global__ __launch_bounds__(256) void coarse_v3(
    const float* __restrict__ feat, const float* __restrict__ cw,
    const float* __restrict__ cb, float* __restrict__ out0,
    float* __restrict__ out1, int* __restrict__ eidArr, int* __restrict__ cnt,
    int* __restrict__ done, int* __restrict__ rowList,
    int* __restrict__ sched, int* __restrict__ nItems, int trE) {
  __shared__ float wS[E_ * 256];  // 16 KB: cw chunk [e][256]
  __shared__ int lcnt[E_];
  __shared__ int lbase[E_];
  __shared__ int rowE[8];
  __shared__ int rowP[8];
  __shared__ int lastFlag;

  const int tid = threadIdx.x;
  const int lane = tid & 63;
  const int wv = tid >> 6;
  if (tid < E_) lcnt[tid] = 0;
  if (tid == 0) lastFlag = 0;

  const int rowBase = blockIdx.x * 8 + wv * 2;
  const int le = ((lane & 1) << 3) | ((lane & 2) << 1) | ((lane & 4) >> 1) |
                 ((lane & 8) >> 3);
  const float cbr = cb[le];

  const float* rp = feat + (size_t)rowBase * D_ + lane * 4;

  float acc[2][16];
#pragma unroll
  for (int r = 0; r < 2; ++r)
#pragma unroll
    for (int j = 0; j < 16; ++j) acc[r][j] = 0.f;

  for (int ch = 0; ch < 8; ++ch) {  // 8 chunks of 256 K
    __syncthreads();  // previous chunk's readers done (covers lcnt init too)
    // transient staging: load -> LDS, nothing lives past the next barrier
    float4 pw[4];
#pragma unroll
    for (int j = 0; j < 4; ++j) {
      const int s = tid + j * 256;  // slot: e = s>>6, float4-col = s&63
      pw[j] = *(const float4*)(cw + (size_t)(s >> 6) * D_ + ch * 256 +
                               (s & 63) * 4);
    }
    float4 f[2];
#pragma unroll
    for (int r = 0; r < 2; ++r)
      f[r] = *(const float4*)(rp + (size_t)r * D_ + ch * 256);
#pragma unroll
    for (int j = 0; j < 4; ++j) ((float4*)wS)[tid + j * 256] = pw[j];
    __syncthreads();  // wS visible (implicit vmcnt drain covers f too)
#pragma unroll
    for (int e = 0; e < E_; ++e) {
      const float4 w = ((const float4*)wS)[e * 64 + lane];
#pragma unroll
      for (int r = 0; r < 2; ++r) {
        acc[r][e] += f[r].x * w.x;
        acc[r][e] += f[r].y * w.y;
        acc[r][e] += f[r].z * w.z;
        acc[r][e] += f[r].w * w.w;
      }
    }
  }

  // per-row: split-halves shuffle reduction + bias + argmax + compaction
#pragma unroll
  for (int r = 0; r < 2; ++r) {
    float v[16];
#pragma unroll
    for (int j = 0; j < 16; ++j) v[j] = acc[r][j];
    {
      const bool hi = lane & 1;
#pragma unroll
      for (int j = 0; j < 8; ++j) {
        const float a = v[j], b = v[j + 8];
        v[j] = hi ? b : a;
        v[j + 8] = hi ? a : b;
      }
#pragma unroll
      for (int j = 0; j < 8; ++j) v[j] += __shfl_xor(v[j + 8], 1);
    }
    {
      const bool hi = lane & 2;
#pragma unroll
      for (int j = 0; j < 4; ++j) {
        const float a = v[j], b = v[j + 4];
        v[j] = hi ? b : a;
        v[j + 4] = hi ? a : b;
      }
#pragma unroll
      for (int j = 0; j < 4; ++j) v[j] += __shfl_xor(v[j + 4], 2);
    }
    {
      const bool hi = lane & 4;
#pragma unroll
      for (int j = 0; j < 2; ++j) {
        const float a = v[j], b = v[j + 2];
        v[j] = hi ? b : a;
        v[j + 2] = hi ? a : b;
      }
#pragma unroll
      for (int j = 0; j < 2; ++j) v[j] += __shfl_xor(v[j + 2], 4);
    }
    {
      const bool hi = lane & 8;
      const float a = v[0], b = v[1];
      v[0] = hi ? b : a;
      v[1] = hi ? a : b;
      v[0] += __shfl_xor(v[1], 8);
    }
    v[0] += __shfl_xor(v[0], 16);
    v[0] += __shfl_xor(v[0], 32);
    const float val = v[0] + cbr;

    const int row = rowBase + r;
    if (lane < 16) out0[(size_t)row * E_ + le] = val;

    float mv = val;
    int mi = le;
#pragma unroll
    for (int d = 1; d <= 8; d <<= 1) {
      const float ov = __shfl_xor(mv, d);
      const int oi = __shfl_xor(mi, d);
      if (ov > mv || (ov == mv && oi < mi)) {
        mv = ov;
        mi = oi;
      }
    }
    if (lane == 0) {
      out1[row] = (float)mi;
      eidArr[row] = mi;
      const int p = atomicAdd(&lcnt[mi], 1);
      rowE[wv * 2 + r] = mi;
      rowP[wv * 2 + r] = p;
    }
  }
  __syncthreads();
  if (tid < E_) lbase[tid] = atomicAdd(&cnt[tid], lcnt[tid]);
  __syncthreads();
  if (tid < 8) {
    const int e = rowE[tid], p = rowP[tid];
    rowList[e * B_ + lbase[e] + p] = blockIdx.x * 8 + tid;
  }

  // last block builds the (e,tile) schedule for the expert GEMM
  __threadfence();
  if (tid == 0)
    if (atomicAdd(done, 1) == (int)gridDim.x - 1) lastFlag = 1;
  __syncthreads();
  if (lastFlag) {
    if (tid < E_) lcnt[tid] = (atomicAdd(&cnt[tid], 0) + trE - 1) / trE;
    __syncthreads();
    if (tid == 0) {
      int a = 0;
      for (int e = 0; e < E_; ++e) {
        lbase[e] = a;
        a += lcnt[e];
      }
      *nItems = a;
    }
    __syncthreads();
    if (tid < E_) {
      const int o = lbase[tid], n = lcnt[tid];
      for (int k = 0; k < n; ++k) sched[o + k] = tid | (k << 8);
    }
  }
}

// ---------------- expert GEMM: 8 x CPT register tile ----------------
// part[kz][row][c] = sum_{kz K-range} feat[grow][d]*W[c][d].  TR = 32*CPT
// rows, 64 cols. Transposed+XOR-swizzled LDS tiles (<=2-way bank aliasing).
// Staging via TRANSIENT 4-float4 phases (no regs live across barriers).
template <int CPT, int SK>
__global__ __launch_bounds__(256) void gemm_expert(
    const float* __restrict__ feat, const float* __restrict__ Wall,
    const int* __restrict__ rowList, const int* __restrict__ cnt,
    const int* __restrict__ sched, const int* __restrict__ nItems,
    float* __restrict__ part0, float* __restrict__ partRest) {
  constexpr int TR = 32 * CPT;   // 256 (CPT=8) or 128 (CPT=4)
  constexpr int NC = C_;
  constexpr int KCH = 32;
  constexpr int FITER = TR / 32;  // 8 or 4
  constexpr int CG = NC / CPT;    // 8 or 16

  __shared__ float fT[KCH * TR];  // 32 / 16 KB
  __shared__ float wT[KCH * NC];  // 8 KB
  __shared__ int rIdx[TR];

  const int tid = threadIdx.x;
  const int b = blockIdx.x;
  const int kz = b % SK;
  const int item = b / SK;
  if (item >= *nItems) return;
  const int s = sched[item];
  const int e = s & 255;
  const int tile = s >> 8;
  const int count = cnt[e];

  if (tid < TR) {
    const int slot = tile * TR + tid;
    rIdx[tid] = (slot < count) ? rowList[e * B_ + slot] : 0;
  }
  __syncthreads();

  unsigned grows[FITER];
#pragma unroll
  for (int i = 0; i < FITER; ++i) grows[i] = (unsigned)rIdx[(i * 256 + tid) >> 3];

  const int cg = tid % CG;
  const int rg = tid / CG;  // row block 0..TR/8-1

  float acc[8][CPT];
#pragma unroll
  for (int r = 0; r < 8; ++r)
#pragma unroll
    for (int c = 0; c < CPT; ++c) acc[r][c] = 0.f;

  const float* We = Wall + (size_t)e * NC * D_;
  constexpr int KRANGE = D_ / SK;
  constexpr int NCH = KRANGE / KCH;
  const int k0 = kz * KRANGE;

  for (int ch = 0; ch < NCH; ++ch) {
    const int kb = k0 + ch * KCH;
    // ---- stage features in 4-load phases (transient registers) ----
#pragma unroll
    for (int h = 0; h < FITER; h += 4) {
      float4 t[4];
#pragma unroll
      for (int q = 0; q < 4; ++q) {
        const int idx = (h + q) * 256 + tid;
        t[q] = *(const float4*)(feat + (size_t)grows[h + q] * D_ + kb +
                                (idx & 7) * 4);
      }
#pragma unroll
      for (int q = 0; q < 4; ++q) {
        const int idx = (h + q) * 256 + tid;
        const int rl = idx >> 3, dcf = idx & 7;
        const int sb = (((rl >> 3) ^ dcf) << 3) + (rl & 7);
        float* p = &fT[(dcf * 4) * TR + sb];
        p[0 * TR] = t[q].x;
        p[1 * TR] = t[q].y;
        p[2 * TR] = t[q].z;
        p[3 * TR] = t[q].w;
      }
    }
    // ---- stage weights (2 float4, transient) ----
    {
      float4 u[2];
#pragma unroll
      for (int i = 0; i < 2; ++i) {
        const int idx = i * 256 + tid;
        u[i] = *(const float4*)(We + (size_t)(idx >> 3) * D_ + kb +
                                (idx & 7) * 4);
      }
#pragma unroll
      for (int i = 0; i < 2; ++i) {
        const int idx = i * 256 + tid;
        const int c = idx >> 3, dcf = idx & 7;
        const int sb = (((c >> 3) ^ dcf) << 3) + (c & 7);
        float* p = &wT[(dcf * 4) * NC + sb];
        p[0 * NC] = u[i].x;
        p[1 * NC] = u[i].y;
        p[2 * NC] = u[i].z;
        p[3 * NC] = u[i].w;
      }
    }
    __syncthreads();
    // ---- compute ----
#pragma unroll
    for (int dd = 0; dd < KCH; ++dd) {
      const int sz = dd >> 2;  // 0..7, matches staging dcf
      float a[8], bb[CPT];
      {
        const float4 v0 = *(const float4*)&fT[dd * TR + ((rg ^ sz) << 3)];
        const float4 v1 = *(const float4*)&fT[dd * TR + ((rg ^ sz) << 3) + 4];
        a[0] = v0.x; a[1] = v0.y; a[2] = v0.z; a[3] = v0.w;
        a[4] = v1.x; a[5] = v1.y; a[6] = v1.z; a[7] = v1.w;
      }
      if constexpr (CPT == 8) {
        const float4 v0 = *(const float4*)&wT[dd * NC + ((cg ^ sz) << 3)];
        const float4 v1 = *(const float4*)&wT[dd * NC + ((cg ^ sz) << 3) + 4];
        bb[0] = v0.x; bb[1] = v0.y; bb[2] = v0.z; bb[3] = v0.w;
        bb[4] = v1.x; bb[5] = v1.y; bb[6] = v1.z; bb[7] = v1.w;
      } else {  // CPT == 4: cols cg*4..+3 live in block cg>>1, half cg&1
        const float4 v0 = *(const float4*)&wT[dd * NC + (((cg >> 1) ^ sz) << 3) +
                                              (cg & 1) * 4];
        bb[0] = v0.x; bb[1] = v0.y; bb[2] = v0.z; bb[3] = v0.w;
      }
#pragma unroll
      for (int r = 0; r < 8; ++r)
#pragma unroll
        for (int c = 0; c < CPT; ++c) acc[r][c] += a[r] * bb[c];
    }
    __syncthreads();
  }

  float* pk = kz ? (partRest + (size_t)(kz - 1) * B_ * NC) : part0;
#pragma unroll
  for (int r = 0; r < 8; ++r) {
    const int lrow = rg * 8 + r;
    const int slot = tile * TR + lrow;
    if (slot < count) {
      const int grow = rIdx[lrow];
      float* dst = pk + (size_t)grow * NC + cg * CPT;
      *(float4*)dst = make_float4(acc[r][0], acc[r][1], acc[r][2], acc[r][3]);
      if constexpr (CPT == 8)
        *(float4*)(dst + 4) =
            make_float4(acc[r][4], acc[r][5], acc[r][6], acc[r][7]);
    }
  }
}

// Wave-per-row: reduce y partials (fixed order), bias, softmax, argmax+start.
template <int SK>
__global__ __launch_bounds__(256) void finish_rows(
    const float* __restrict__ ypart0, const float* __restrict__ ypartRest,
    const float* __restrict__ eb, const int* __restrict__ eidArr,
    float* __restrict__ out2, float* __restrict__ out3) {
  const int lane = threadIdx.x & 63;
  const int row = (blockIdx.x * 256 + threadIdx.x) >> 6;
  const int eid = eidArr[row];

  float v = eb[eid * C_ + lane];
  v += ypart0[(size_t)row * C_ + lane];
#pragma unroll
  for (int kz = 1; kz < SK; ++kz)
    v += ypartRest[((size_t)(kz - 1) * B_ + row) * C_ + lane];

  float m = v;
#pragma unroll
  for (int off = 32; off; off >>= 1) m = fmaxf(m, __shfl_xor(m, off));
  const float p = __expf(v - m);
  float s = p;
#pragma unroll
  for (int off = 32; off; off >>= 1) s += __shfl_xor(s, off);
  out2[(size_t)row * C_ + lane] = p / s;  // ypart0 aliases out2; read done

  float av = v;
  int ai = lane;
#pragma unroll
  for (int off = 32; off; off >>= 1) {
    const float ov = __shfl_xor(av, off);
    const int oi = __shfl_xor(ai, off);
    if (ov > av || (ov == av && oi < ai)) {
      av = ov;
      ai = oi;
    }
  }
  if (lane == 0) out3[row] = (float)(ai + (eid << 6));
}

extern "C" void kernel_launch(void* const* d_in, const int* in_sizes, int n_in,
                              void* d_out, int out_size, void* d_ws,
                              size_t ws_size, hipStream_t stream) {
  const float* feat = (const float*)d_in[0];  // [B, D]
  const float* cw = (const float*)d_in[1];    // [E, D]
  const float* cb = (const float*)d_in[2];    // [E]
  const float* ew = (const float*)d_in[3];    // [E, C, D]
  const float* eb = (const float*)d_in[4];    // [E, C]

  float* out0 = (float*)d_out;           // coarse_output [B, E]
  float* out1 = out0 + (size_t)B_ * E_;  // expert_id [B] (as float)
  float* out2 = out1 + B_;               // local_preds [B, C]
  float* out3 = out2 + (size_t)B_ * C_;  // global_preds [B]

  // ws: expert kz>=1 partials + routing metadata. SK=8/TR=256 needs ~30.5MB;
  // fall back to SK=4/TR=128 (~13.8 MB, within the R1-proven budget).
  const size_t metaBytes = (size_t)E_ * B_ * 4 + 256 + (size_t)B_ * 4 + 4096;
  const bool sk8 = ws_size >= (size_t)7 * B_ * C_ * 4 + metaBytes;
  const int SK = sk8 ? 8 : 4;
  const int trE = sk8 ? 256 : 128;

  char* ws = (char*)d_ws;
  float* ypartRest = (float*)ws;  // (SK-1)*B*C
  int* rowList = (int*)(ypartRest + (size_t)(SK - 1) * B_ * C_);  // E*B
  int* cnt = rowList + (size_t)E_ * B_;  // 16 counts; done @ +16 (pad 64)
  int* done = cnt + E_;
  int* eidArr = cnt + 64;  // B
  int* sched = eidArr + B_;  // schedule (pad 512)
  int* nItems = sched + 512;

  hipMemsetAsync(cnt, 0, 256, stream);  // cnt[0..15] + done

  // 1) fused coarse: GEMM + argmax + compaction + schedule (2048 blocks)
  coarse_v3<<<B_ / 8, 256, 0, stream>>>(feat, cw, cb, out0, out1, eidArr, cnt,
                                        done, rowList, sched, nItems, trE);
  // 2) expert GEMM, dense flat-scheduled grid (kz==0 slice aliases out2)
  if (sk8)
    gemm_expert<8, 8><<<(B_ / 256 + E_) * 8, 256, 0, stream>>>(
        feat, ew, rowList, cnt, sched, nItems, out2, ypartRest);
  else
    gemm_expert<4, 4><<<(B_ / 128 + E_) * 4, 256, 0, stream>>>(
        feat, ew, rowList, cnt, sched, nItems, out2, ypartRest);
  // 3) softmax + argmax + class-range start
  if (sk8)
    finish_rows<8><<<(B_ * 64) / 256, 256, 0, stream>>>(out2, ypartRest, eb,
                                                        eidArr, out2, out3);
  else
    finish_rows<4><<<(B_ * 64) / 256, 256, 0, stream>>>(out2, ypartRest, eb,
                                                        eidArr, out2, out3);
}

// Round 8
// 360.154 us; speedup vs baseline: 1.2818x; 1.2818x over previous
//
#include <hip/hip_runtime.h>
#include <cstdint>

// MoE: B=16384 rows, D=2048 feat, E=16 experts, C=64 classes/expert.
// All math fp32 (argmax outputs can't tolerate bf16 error vs np reference).
// R8: (a) NO device atomics in wide kernels — R7's 2048-block fused coarse
// spent ~200us on 33K contended same-line atomics (VALU 7%, nothing busy);
// compaction moves to a 64-block kernel (1K atomics, proven cheap in R1-R3).
// (b) register prefetch restored everywhere (R7 transient staging exposed
// full mem latency); __launch_bounds__(256,1) lifts the compiler's default
// ~80-VGPR cap that caused R6's squeeze-spill. (c) expert 8x4 tile: DS:VALU
// 2.25:1 vs 3:1 at 4x4 (DS pipe is per-CU, VALU per-SIMD; model matches
// R3=78us and R5=98us).
static constexpr int B_ = 16384;
static constexpr int D_ = 2048;
static constexpr int E_ = 16;
static constexpr int C_ = 64;

// ---------------- coarse GEMM (no atomics) ----------------
// Block = 8 rows (4 waves x 2 rows), 2048 blocks. Lanes span K (float4
// coalesced, features read once from HBM). Weight K-chunk (16x256 = 16 KB)
// staged in LDS; next chunk's weights+features prefetched into registers
// during compute. Epilogue: split-halves shuffle reduction (lane owns expert
// bitrev4(lane&15)), bias, argmax; writes out0/out1/eidArr. Verified R4-R7.
__global__ __launch_bounds__(256, 1) void coarse_gemm(
    const float* __restrict__ feat, const float* __restrict__ cw,
    const float* __restrict__ cb, float* __restrict__ out0,
    float* __restrict__ out1, int* __restrict__ eidArr) {
  __shared__ float wS[E_ * 256];  // 16 KB

  const int tid = threadIdx.x;
  const int lane = tid & 63;
  const int wv = tid >> 6;

  const int rowBase = blockIdx.x * 8 + wv * 2;
  const int le = ((lane & 1) << 3) | ((lane & 2) << 1) | ((lane & 4) >> 1) |
                 ((lane & 8) >> 3);
  const float cbr = cb[le];

  const float* rp = feat + (size_t)rowBase * D_ + lane * 4;

  float acc[2][16];
#pragma unroll
  for (int r = 0; r < 2; ++r)
#pragma unroll
    for (int j = 0; j < 16; ++j) acc[r][j] = 0.f;

  // prefetch chunk 0
  float4 pw[4], fn[2];
#pragma unroll
  for (int j = 0; j < 4; ++j) {
    const int s = tid + j * 256;  // slot: e = s>>6, float4-col = s&63
    pw[j] = *(const float4*)(cw + (size_t)(s >> 6) * D_ + (s & 63) * 4);
  }
#pragma unroll
  for (int r = 0; r < 2; ++r) fn[r] = *(const float4*)(rp + (size_t)r * D_);

  for (int ch = 0; ch < 8; ++ch) {  // 8 chunks of 256 K
    __syncthreads();  // previous chunk's wS readers done
#pragma unroll
    for (int j = 0; j < 4; ++j) ((float4*)wS)[tid + j * 256] = pw[j];
    float4 f[2];
#pragma unroll
    for (int r = 0; r < 2; ++r) f[r] = fn[r];
    __syncthreads();  // wS ready
    if (ch < 7) {     // prefetch next chunk; overlaps compute below
      const int kb = (ch + 1) * 256;
#pragma unroll
      for (int j = 0; j < 4; ++j) {
        const int s = tid + j * 256;
        pw[j] = *(const float4*)(cw + (size_t)(s >> 6) * D_ + kb + (s & 63) * 4);
      }
#pragma unroll
      for (int r = 0; r < 2; ++r)
        fn[r] = *(const float4*)(rp + (size_t)r * D_ + kb);
    }
#pragma unroll
    for (int e = 0; e < E_; ++e) {
      const float4 w = ((const float4*)wS)[e * 64 + lane];
#pragma unroll
      for (int r = 0; r < 2; ++r) {
        acc[r][e] += f[r].x * w.x;
        acc[r][e] += f[r].y * w.y;
        acc[r][e] += f[r].z * w.z;
        acc[r][e] += f[r].w * w.w;
      }
    }
  }

  // per-row: split-halves shuffle reduction + bias + argmax
#pragma unroll
  for (int r = 0; r < 2; ++r) {
    float v[16];
#pragma unroll
    for (int j = 0; j < 16; ++j) v[j] = acc[r][j];
    {
      const bool hi = lane & 1;
#pragma unroll
      for (int j = 0; j < 8; ++j) {
        const float a = v[j], b = v[j + 8];
        v[j] = hi ? b : a;
        v[j + 8] = hi ? a : b;
      }
#pragma unroll
      for (int j = 0; j < 8; ++j) v[j] += __shfl_xor(v[j + 8], 1);
    }
    {
      const bool hi = lane & 2;
#pragma unroll
      for (int j = 0; j < 4; ++j) {
        const float a = v[j], b = v[j + 4];
        v[j] = hi ? b : a;
        v[j + 4] = hi ? a : b;
      }
#pragma unroll
      for (int j = 0; j < 4; ++j) v[j] += __shfl_xor(v[j + 4], 2);
    }
    {
      const bool hi = lane & 4;
#pragma unroll
      for (int j = 0; j < 2; ++j) {
        const float a = v[j], b = v[j + 2];
        v[j] = hi ? b : a;
        v[j + 2] = hi ? a : b;
      }
#pragma unroll
      for (int j = 0; j < 2; ++j) v[j] += __shfl_xor(v[j + 2], 4);
    }
    {
      const bool hi = lane & 8;
      const float a = v[0], b = v[1];
      v[0] = hi ? b : a;
      v[1] = hi ? a : b;
      v[0] += __shfl_xor(v[1], 8);
    }
    v[0] += __shfl_xor(v[0], 16);
    v[0] += __shfl_xor(v[0], 32);
    const float val = v[0] + cbr;

    const int row = rowBase + r;
    if (lane < 16) out0[(size_t)row * E_ + le] = val;

    float mv = val;
    int mi = le;
#pragma unroll
    for (int d = 1; d <= 8; d <<= 1) {
      const float ov = __shfl_xor(mv, d);
      const int oi = __shfl_xor(mi, d);
      if (ov > mv || (ov == mv && oi < mi)) {
        mv = ov;
        mi = oi;
      }
    }
    if (lane == 0) {
      out1[row] = (float)mi;
      eidArr[row] = mi;
    }
  }
}

// ---------------- compaction + schedule (64 blocks, cheap atomics) --------
__global__ __launch_bounds__(256) void compact_rows(
    const int* __restrict__ eidArr, int* __restrict__ cnt,
    int* __restrict__ done, int* __restrict__ rowList,
    int* __restrict__ sched, int* __restrict__ nItems, int trE) {
  __shared__ int lcnt[E_];
  __shared__ int lbase[E_];
  __shared__ int lastFlag;
  const int tid = threadIdx.x;
  if (tid < E_) lcnt[tid] = 0;
  if (tid == 0) lastFlag = 0;
  __syncthreads();

  const int row = blockIdx.x * 256 + tid;
  const int eid = eidArr[row];
  const int lpos = atomicAdd(&lcnt[eid], 1);
  __syncthreads();
  if (tid < E_) lbase[tid] = atomicAdd(&cnt[tid], lcnt[tid]);
  __syncthreads();
  rowList[eid * B_ + lbase[eid] + lpos] = row;

  __threadfence();
  if (tid == 0)
    if (atomicAdd(done, 1) == (int)gridDim.x - 1) lastFlag = 1;
  __syncthreads();
  if (lastFlag) {
    if (tid < E_) lcnt[tid] = (atomicAdd(&cnt[tid], 0) + trE - 1) / trE;
    __syncthreads();
    if (tid == 0) {
      int a = 0;
      for (int e = 0; e < E_; ++e) {
        lbase[e] = a;
        a += lcnt[e];
      }
      *nItems = a;
    }
    __syncthreads();
    if (tid < E_) {
      const int o = lbase[tid], n = lcnt[tid];
      for (int k = 0; k < n; ++k) sched[o + k] = tid | (k << 8);
    }
  }
}

// ---------------- expert GEMM: RPT x 4 register tile ----------------
// part[kz][row][c] = sum_{kz K-range} feat[grow][d]*W[c][d].  TR = RPT*16
// rows x 64 cols; transposed+XOR-swizzled LDS tiles; register prefetch of
// the next K-chunk (R3-proven pattern). DS reads per dd per wave: RPT/4+1
// b128 (a-reads broadcast across the 16 lanes sharing rg).
template <int RPT, int SK>
__global__ __launch_bounds__(256, 1) void gemm_expert(
    const float* __restrict__ feat, const float* __restrict__ Wall,
    const int* __restrict__ rowList, const int* __restrict__ cnt,
    const int* __restrict__ sched, const int* __restrict__ nItems,
    float* __restrict__ part0, float* __restrict__ partRest) {
  constexpr int TR = RPT * 16;    // 128 (RPT=8) or 64 (RPT=4)
  constexpr int NC = C_;
  constexpr int KCH = 32;
  constexpr int FITER = TR / 32;  // 4 or 2
  constexpr int RB = TR / 8;

  __shared__ float fT[KCH * TR];  // 16 / 8 KB
  __shared__ float wT[KCH * NC];  // 8 KB
  __shared__ int rIdx[TR];

  const int tid = threadIdx.x;
  const int b = blockIdx.x;
  const int kz = b % SK;
  const int item = b / SK;
  if (item >= *nItems) return;
  const int s = sched[item];
  const int e = s & 255;
  const int tile = s >> 8;
  const int count = cnt[e];

  if (tid < TR) {
    const int slot = tile * TR + tid;
    rIdx[tid] = (slot < count) ? rowList[e * B_ + slot] : 0;
  }
  __syncthreads();

  unsigned grows[FITER];
  int dcf[FITER], sbf[FITER];
#pragma unroll
  for (int i = 0; i < FITER; ++i) {
    const int idx = i * 256 + tid;
    const int rl = idx >> 3;
    dcf[i] = idx & 7;
    grows[i] = (unsigned)rIdx[rl];
    sbf[i] = (((rl >> 3) ^ dcf[i]) << 3) + (rl & 7);
  }

  const int cg = tid & 15;   // col group: cols cg*4..+3
  const int rg = tid >> 4;   // row group: rows rg*RPT..

  float acc[RPT][4];
#pragma unroll
  for (int r = 0; r < RPT; ++r)
#pragma unroll
    for (int c = 0; c < 4; ++c) acc[r][c] = 0.f;

  const float* We = Wall + (size_t)e * NC * D_;
  constexpr int KRANGE = D_ / SK;
  constexpr int NCH = KRANGE / KCH;
  const int k0 = kz * KRANGE;

  // prefetch chunk 0
  float4 pf[FITER], pw[2];
#pragma unroll
  for (int i = 0; i < FITER; ++i)
    pf[i] = *(const float4*)(feat + (size_t)grows[i] * D_ + k0 + dcf[i] * 4);
#pragma unroll
  for (int i = 0; i < 2; ++i) {
    const int idx = i * 256 + tid;
    pw[i] = *(const float4*)(We + (size_t)(idx >> 3) * D_ + k0 + (idx & 7) * 4);
  }

  for (int ch = 0; ch < NCH; ++ch) {
    // drain prefetch -> LDS (transposed + swizzled)
#pragma unroll
    for (int i = 0; i < FITER; ++i) {
      float* p = &fT[(dcf[i] * 4) * TR + sbf[i]];
      p[0 * TR] = pf[i].x;
      p[1 * TR] = pf[i].y;
      p[2 * TR] = pf[i].z;
      p[3 * TR] = pf[i].w;
    }
#pragma unroll
    for (int i = 0; i < 2; ++i) {
      const int idx = i * 256 + tid;
      const int c = idx >> 3, wdc = idx & 7;
      const int sb = (((c >> 3) ^ wdc) << 3) + (c & 7);
      float* p = &wT[(wdc * 4) * NC + sb];
      p[0 * NC] = pw[i].x;
      p[1 * NC] = pw[i].y;
      p[2 * NC] = pw[i].z;
      p[3 * NC] = pw[i].w;
    }
    __syncthreads();
    if (ch + 1 < NCH) {  // prefetch next chunk; overlaps dd-loop
      const int kb = k0 + (ch + 1) * KCH;
#pragma unroll
      for (int i = 0; i < FITER; ++i)
        pf[i] = *(const float4*)(feat + (size_t)grows[i] * D_ + kb + dcf[i] * 4);
#pragma unroll
      for (int i = 0; i < 2; ++i) {
        const int idx = i * 256 + tid;
        pw[i] =
            *(const float4*)(We + (size_t)(idx >> 3) * D_ + kb + (idx & 7) * 4);
      }
    }
#pragma unroll
    for (int dd = 0; dd < KCH; ++dd) {
      const int sz = dd >> 2;  // matches staging dcf group
      float a[RPT], bb[4];
      if constexpr (RPT == 8) {
        const float4 v0 = *(const float4*)&fT[dd * TR + ((rg ^ sz) << 3)];
        const float4 v1 = *(const float4*)&fT[dd * TR + ((rg ^ sz) << 3) + 4];
        a[0] = v0.x; a[1] = v0.y; a[2] = v0.z; a[3] = v0.w;
        a[4] = v1.x; a[5] = v1.y; a[6] = v1.z; a[7] = v1.w;
      } else {  // RPT == 4: rows rg*4..+3 -> block rg>>1, half rg&1
        const float4 v0 = *(const float4*)&fT[dd * TR + (((rg >> 1) ^ sz) << 3) +
                                              (rg & 1) * 4];
        a[0] = v0.x; a[1] = v0.y; a[2] = v0.z; a[3] = v0.w;
      }
      {
        const float4 v0 = *(const float4*)&wT[dd * NC + (((cg >> 1) ^ sz) << 3) +
                                              (cg & 1) * 4];
        bb[0] = v0.x; bb[1] = v0.y; bb[2] = v0.z; bb[3] = v0.w;
      }
#pragma unroll
      for (int r = 0; r < RPT; ++r)
#pragma unroll
        for (int c = 0; c < 4; ++c) acc[r][c] += a[r] * bb[c];
    }
    __syncthreads();
  }

  float* pk = kz ? (partRest + (size_t)(kz - 1) * B_ * NC) : part0;
#pragma unroll
  for (int r = 0; r < RPT; ++r) {
    const int lrow = rg * RPT + r;
    const int slot = tile * TR + lrow;
    if (slot < count) {
      const int grow = rIdx[lrow];
      float* dst = pk + (size_t)grow * NC + cg * 4;
      *(float4*)dst = make_float4(acc[r][0], acc[r][1], acc[r][2], acc[r][3]);
    }
  }
}

// Wave-per-row: reduce y partials (fixed order), bias, softmax, argmax+start.
template <int SK>
__global__ __launch_bounds__(256) void finish_rows(
    const float* __restrict__ ypart0, const float* __restrict__ ypartRest,
    const float* __restrict__ eb, const int* __restrict__ eidArr,
    float* __restrict__ out2, float* __restrict__ out3) {
  const int lane = threadIdx.x & 63;
  const int row = (blockIdx.x * 256 + threadIdx.x) >> 6;
  const int eid = eidArr[row];

  float v = eb[eid * C_ + lane];
  v += ypart0[(size_t)row * C_ + lane];
#pragma unroll
  for (int kz = 1; kz < SK; ++kz)
    v += ypartRest[((size_t)(kz - 1) * B_ + row) * C_ + lane];

  float m = v;
#pragma unroll
  for (int off = 32; off; off >>= 1) m = fmaxf(m, __shfl_xor(m, off));
  const float p = __expf(v - m);
  float s = p;
#pragma unroll
  for (int off = 32; off; off >>= 1) s += __shfl_xor(s, off);
  out2[(size_t)row * C_ + lane] = p / s;  // ypart0 aliases out2; read done

  float av = v;
  int ai = lane;
#pragma unroll
  for (int off = 32; off; off >>= 1) {
    const float ov = __shfl_xor(av, off);
    const int oi = __shfl_xor(ai, off);
    if (ov > av || (ov == av && oi < ai)) {
      av = ov;
      ai = oi;
    }
  }
  if (lane == 0) out3[row] = (float)(ai + (eid << 6));
}

extern "C" void kernel_launch(void* const* d_in, const int* in_sizes, int n_in,
                              void* d_out, int out_size, void* d_ws,
                              size_t ws_size, hipStream_t stream) {
  const float* feat = (const float*)d_in[0];  // [B, D]
  const float* cw = (const float*)d_in[1];    // [E, D]
  const float* cb = (const float*)d_in[2];    // [E]
  const float* ew = (const float*)d_in[3];    // [E, C, D]
  const float* eb = (const float*)d_in[4];    // [E, C]

  float* out0 = (float*)d_out;           // coarse_output [B, E]
  float* out1 = out0 + (size_t)B_ * E_;  // expert_id [B] (as float)
  float* out2 = out1 + B_;               // local_preds [B, C]
  float* out3 = out2 + (size_t)B_ * C_;  // global_preds [B]

  // ws: expert kz>=1 partials + routing metadata. SK=8/TR=128 needs ~30.6MB;
  // fall back to SK=4/TR=64 (R3-proven, ~13.8 MB).
  const size_t metaBytes = (size_t)E_ * B_ * 4 + 256 + (size_t)B_ * 4 + 4096;
  const bool sk8 = ws_size >= (size_t)7 * B_ * C_ * 4 + metaBytes;
  const int SK = sk8 ? 8 : 4;
  const int trE = sk8 ? 128 : 64;

  char* ws = (char*)d_ws;
  float* ypartRest = (float*)ws;  // (SK-1)*B*C
  int* rowList = (int*)(ypartRest + (size_t)(SK - 1) * B_ * C_);  // E*B
  int* cnt = rowList + (size_t)E_ * B_;  // 16 counts; done @ +16 (pad 64)
  int* done = cnt + E_;
  int* eidArr = cnt + 64;    // B
  int* sched = eidArr + B_;  // schedule (pad 512)
  int* nItems = sched + 512;

  hipMemsetAsync(cnt, 0, 256, stream);  // cnt[0..15] + done

  // 1) coarse GEMM (no atomics): out0, out1, eidArr
  coarse_gemm<<<B_ / 8, 256, 0, stream>>>(feat, cw, cb, out0, out1, eidArr);
  // 2) compaction + schedule build (64 blocks — cheap atomic regime)
  compact_rows<<<B_ / 256, 256, 0, stream>>>(eidArr, cnt, done, rowList, sched,
                                             nItems, trE);
  // 3) expert GEMM over dense flat-scheduled grid (kz==0 aliases out2)
  if (sk8)
    gemm_expert<8, 8><<<(B_ / 128 + E_) * 8, 256, 0, stream>>>(
        feat, ew, rowList, cnt, sched, nItems, out2, ypartRest);
  else
    gemm_expert<4, 4><<<(B_ / 64 + E_) * 4, 256, 0, stream>>>(
        feat, ew, rowList, cnt, sched, nItems, out2, ypartRest);
  // 4) softmax + argmax + class-range start
  if (sk8)
    finish_rows<8><<<(B_ * 64) / 256, 256, 0, stream>>>(out2, ypartRest, eb,
                                                        eidArr, out2, out3);
  else
    finish_rows<4><<<(B_ * 64) / 256, 256, 0, stream>>>(out2, ypartRest, eb,
                                                        eidArr, out2, out3);
}